// Round 4
// baseline (139.188 us; speedup 1.0000x reference)
//
#include <hip/hip_runtime.h>
#include <math.h>

// B=2048, L=64. out = sum(kl) + (BETA-1)*mean_i(log_qz_i - log_qz_product_i)
// lp2[i,j,l] = lp/ln2 = a2*d^2 + b2, d = z_i_l - m_j_l, a2 = -0.5/ln2*exp(-lv) < 0
// k3-part: single-pass LSE with constant shift BVAL (lp2 <= b2 << BVAL, validated).
// Horner: lp2 - BVAL = fma(fma(z, a2, c1), z, c0'), c1=-2*a2*m, c0'=a2*m^2+b2-BVAL.
// t-part (k2): t2_ij = dot(z^2, a2) + dot(z, c1) + qc2_j, real max (range too wide
// for a constant shift: t2 ~ -240 +- 16).

#define NB 2048
#define NL 64
#define NE (NB * NL)
#define BVAL 12.0f

__device__ __forceinline__ float wredsum(float v) {
#pragma unroll
  for (int o = 32; o; o >>= 1) v += __shfl_xor(v, o, 64);
  return v;
}
__device__ __forceinline__ float wredmax(float v) {
#pragma unroll
  for (int o = 32; o; o >>= 1) v = fmaxf(v, __shfl_xor(v, o, 64));
  return v;
}

// A: coeffs + transposed GEMM arrays + qc2 + kl partials + zero Sacc/counter.
__global__ __launch_bounds__(256) void ka_pre(const float* __restrict__ kl,
                                              const float* __restrict__ zm,
                                              const float* __restrict__ zlv,
                                              float4* __restrict__ PK2,
                                              float* __restrict__ A2T,
                                              float* __restrict__ MA2T,
                                              float* __restrict__ QC2,
                                              float* __restrict__ KLP,
                                              float* __restrict__ Sacc,
                                              int* __restrict__ CNT) {
  const float INVLN2 = 1.4426950408889634f;
  const float LOG2PI = 1.8378770664093453f;
  int tid = threadIdx.x;
  int e = blockIdx.x * 256 + tid;  // < NE
  int j = e >> 6, l = e & 63;
  float lv = zlv[e], m = zm[e];
  float a2 = -0.5f * INVLN2 * __expf(-lv);
  float b2 = -0.5f * INVLN2 * (lv + LOG2PI);
  float c1 = -2.0f * a2 * m;
  float c0 = fmaf(a2 * m, m, b2);
  PK2[e] = make_float4(a2, c1, c0 - BVAL, 0.0f);
  A2T[l * NB + j] = a2;
  MA2T[l * NB + j] = c1;
  Sacc[e] = 0.0f;
  float q = wredsum(c0);
  if (l == 0) QC2[j] = q;
  float ks = wredsum(kl[e]);
  __shared__ float sk[4];
  if (l == 0) sk[tid >> 6] = ks;
  __syncthreads();
  if (tid == 0) KLP[blockIdx.x] = sk[0] + sk[1] + sk[2] + sk[3];
  if (blockIdx.x == 0 && tid == 0) *CNT = 0;
}

// B: fused t-chunk LSE (k2) + per-(i,l) exp2 sum (k3). 2048 blocks:
// jc = bid&7 (256 j's), i-tile = bid>>3 (8 i's). 8 blocks/CU.
__global__ __launch_bounds__(256, 8) void kb_main(const float* __restrict__ zs,
                                                  const float* __restrict__ A2T,
                                                  const float* __restrict__ MA2T,
                                                  const float* __restrict__ QC2,
                                                  const float4* __restrict__ PK2,
                                                  float* __restrict__ TPM,
                                                  float* __restrict__ TPS,
                                                  float* __restrict__ Sacc) {
  int bid = blockIdx.x;
  int jc = bid & 7;
  int i0 = (bid >> 3) * 8;
  int tid = threadIdx.x;
  int w = tid >> 6, l = tid & 63;

  // ---- phase 1: t2 over this (jc, i-tile); thread = one j, 8 i's ----
  __shared__ float zsh[64][8];  // [k][r]
  if (tid < 128) {
    int k = tid >> 1, r0 = (tid & 1) * 4;
#pragma unroll
    for (int r = 0; r < 4; ++r) zsh[k][r0 + r] = zs[(i0 + r0 + r) * NL + k];
  }
  __syncthreads();
  int j = jc * 256 + tid;
  float accv[8];
  float q = QC2[j];
#pragma unroll
  for (int r = 0; r < 8; ++r) accv[r] = q;
  for (int k = 0; k < 64; ++k) {
    float av = A2T[k * NB + j];
    float mv = MA2T[k * NB + j];
    const float4* z4 = (const float4*)&zsh[k][0];
    float4 za = z4[0], zb = z4[1];
    float zk[8] = {za.x, za.y, za.z, za.w, zb.x, zb.y, zb.z, zb.w};
#pragma unroll
    for (int r = 0; r < 8; ++r) {
      accv[r] = fmaf(zk[r] * zk[r], av, accv[r]);
      accv[r] = fmaf(zk[r], mv, accv[r]);
    }
  }
  __shared__ float lm[4][8], ls[4][8];
#pragma unroll
  for (int r = 0; r < 8; ++r) {
    float mx = wredmax(accv[r]);
    if (l == 0) lm[w][r] = mx;
  }
  __syncthreads();
  float Mt[8];
#pragma unroll
  for (int r = 0; r < 8; ++r)
    Mt[r] = fmaxf(fmaxf(lm[0][r], lm[1][r]), fmaxf(lm[2][r], lm[3][r]));
#pragma unroll
  for (int r = 0; r < 8; ++r) {
    float ss = wredsum(__builtin_amdgcn_exp2f(accv[r] - Mt[r]));
    if (l == 0) ls[w][r] = ss;
  }
  __syncthreads();
  if (tid == 0) {
#pragma unroll
    for (int r = 0; r < 8; ++r) {
      TPM[(i0 + r) * 8 + jc] = Mt[r];
      TPS[(i0 + r) * 8 + jc] = ls[0][r] + ls[1][r] + ls[2][r] + ls[3][r];
    }
  }

  // ---- phase 2: per-(i,l) sum_j exp2(lp2 - BVAL); wave w takes 64 j's ----
  const float4* p = PK2 + (size_t)(jc * 256 + w * 64) * NL + l;
  float zr[8];
#pragma unroll
  for (int r = 0; r < 8; ++r) zr[r] = zs[(i0 + r) * NL + l];
  float S[8];
#pragma unroll
  for (int r = 0; r < 8; ++r) S[r] = 0.0f;
#pragma unroll 4
  for (int jj = 0; jj < 64; ++jj) {
    float4 c = p[(size_t)jj * NL];
#pragma unroll
    for (int r = 0; r < 8; ++r) {
      float lp2 = fmaf(fmaf(zr[r], c.x, c.y), zr[r], c.z);
      S[r] += __builtin_amdgcn_exp2f(lp2);
    }
  }
  __shared__ float lss[4][8][64];
#pragma unroll
  for (int r = 0; r < 8; ++r) lss[w][r][l] = S[r];
  __syncthreads();
  for (int pp = tid; pp < 512; pp += 256) {
    int r = pp >> 6, ll = pp & 63;
    float Sc = lss[0][r][ll] + lss[1][r][ll] + lss[2][r][ll] + lss[3][r][ll];
    atomicAdd(&Sacc[(size_t)(i0 + r) * NL + ll], Sc);
  }
}

// C: per-i finish (k4) + last-block global reduce (k5). 512 blocks, wave = one i.
__global__ __launch_bounds__(256) void kc_fin(const float* __restrict__ Sacc,
                                              const float* __restrict__ TPM,
                                              const float* __restrict__ TPS,
                                              const float* __restrict__ KLP,
                                              float* __restrict__ PERB,
                                              int* __restrict__ CNT,
                                              float* __restrict__ out) {
  int tid = threadIdx.x;
  int w = tid >> 6, l = tid & 63;
  int i = blockIdx.x * 4 + w;
  float S = Sacc[(size_t)i * NL + l];
  float val = __builtin_amdgcn_logf(S);  // log2
  float lqp2 = wredsum(val) + 64.0f * BVAL;
  float tm = (l < 8) ? TPM[i * 8 + l] : -1e30f;
  float ts = (l < 8) ? TPS[i * 8 + l] : 0.0f;
  float Mt = wredmax(tm);
  float St = wredsum(ts * __builtin_amdgcn_exp2f(tm - Mt));
  float lqz2 = Mt + __builtin_amdgcn_logf(St);
  __shared__ float sblk[4];
  if (l == 0) sblk[w] = lqz2 - lqp2;
  __syncthreads();
  __shared__ int slast;
  if (tid == 0) {
    float v = sblk[0] + sblk[1] + sblk[2] + sblk[3];
    __hip_atomic_store(&PERB[blockIdx.x], v, __ATOMIC_RELEASE, __HIP_MEMORY_SCOPE_AGENT);
    int old = __hip_atomic_fetch_add(CNT, 1, __ATOMIC_ACQ_REL, __HIP_MEMORY_SCOPE_AGENT);
    slast = (old == 511) ? 1 : 0;
  }
  __syncthreads();
  if (!slast) return;
  float a = 0.0f, b = 0.0f;
  for (int x = tid; x < 512; x += 256) {
    a += KLP[x];
    b += __hip_atomic_load(&PERB[x], __ATOMIC_ACQUIRE, __HIP_MEMORY_SCOPE_AGENT);
  }
  float ra = wredsum(a), rb = wredsum(b);
  __shared__ float sa[4], sb[4];
  if (l == 0) {
    sa[w] = ra;
    sb[w] = rb;
  }
  __syncthreads();
  if (tid == 0) {
    const float LN2 = 0.6931471805599453f;
    float ka = sa[0] + sa[1] + sa[2] + sa[3];
    float kb = sb[0] + sb[1] + sb[2] + sb[3];
    out[0] = ka + 5.0f * LN2 * kb * (1.0f / (float)NB);
  }
}

extern "C" void kernel_launch(void* const* d_in, const int* in_sizes, int n_in,
                              void* d_out, int out_size, void* d_ws, size_t ws_size,
                              hipStream_t stream) {
  const float* kl = (const float*)d_in[0];
  const float* zm = (const float*)d_in[1];
  const float* zlv = (const float*)d_in[2];
  const float* zs = (const float*)d_in[3];
  float* ws = (float*)d_ws;

  float* PK2 = ws;                  // 4*NE
  float* A2T = PK2 + 4 * NE;        // NE
  float* MA2T = A2T + NE;           // NE
  float* QC2 = MA2T + NE;           // NB
  float* Sacc = QC2 + NB;           // NE
  float* TPM = Sacc + NE;           // NB*8
  float* TPS = TPM + NB * 8;        // NB*8
  float* KLP = TPS + NB * 8;        // 512
  float* PERB = KLP + 512;          // 512
  int* CNT = (int*)(PERB + 512);    // 1  (total ~3.8 MB)

  ka_pre<<<NE / 256, 256, 0, stream>>>(kl, zm, zlv, (float4*)PK2, A2T, MA2T, QC2,
                                       KLP, Sacc, CNT);
  kb_main<<<2048, 256, 0, stream>>>(zs, A2T, MA2T, QC2, (const float4*)PK2, TPM,
                                    TPS, Sacc);
  kc_fin<<<512, 256, 0, stream>>>(Sacc, TPM, TPS, KLP, PERB, CNT, (float*)d_out);
}